// Round 17
// baseline (1426.401 us; speedup 1.0000x reference)
//
#include <hip/hip_runtime.h>
#include <cstdint>
#include <cstddef>

#define H_ 64
#define W_ 64
#define T_ 32
#define CIN_ 16
#define COUT_ 64
#define K_ 432
#define NTHR_ 512

// ---- prep: w_g[(g*K_+k)*8 + (c&7)] f32 (wave-contiguous), Gram d64, inv64 ----
__global__ void prep(const float* __restrict__ w, float* __restrict__ w_g,
                     double* __restrict__ d64, double* __restrict__ inv64) {
    const int i = blockIdx.x;   // cout row
    const int j = threadIdx.x;  // 0..63
    const float* wi = w + i * K_;
    const float* wj = w + j * K_;
    double acc = 0.0;
    for (int k = 0; k < K_; ++k) acc += (double)wi[k] * (double)wj[k];
    d64[i * 64 + j] = acc;
    if (i == j) inv64[i] = 1.0 / (acc + 1e-8);
    for (int k = j; k < K_; k += 64)
        w_g[(((i >> 3) * K_) + k) * 8 + (i & 7)] = wi[k];
}

// load 27 window values for one cin (3 z-slices) via global VMEM, mask-multiplied
#define LOADX(CIN, XV) do {                                                      \
    const float* xm_ = xg + (((size_t)(b * 16 + (CIN)) * 32 + zmc) << 12);       \
    const float* x0_ = xg + (((size_t)(b * 16 + (CIN)) * 32 + t  ) << 12);       \
    const float* xp_ = xg + (((size_t)(b * 16 + (CIN)) * 32 + zpc) << 12);       \
    _Pragma("unroll")                                                            \
    for (int j_ = 0; j_ < 9; ++j_) {                                             \
        XV[j_]      = xm_[a9[j_]] * mA[j_];                                      \
        XV[9 + j_]  = x0_[a9[j_]] * m9[j_];                                      \
        XV[18 + j_] = xp_[a9[j_]] * mC[j_];                                      \
    }                                                                            \
} while (0)

// 27x8 FMA chain for one cin (k order = dz,dy,dx ascending, same as R16), fp64 fold
#define FMACIN(CIN, XV) do {                                                     \
    float cacc[8] = {0.f, 0.f, 0.f, 0.f, 0.f, 0.f, 0.f, 0.f};                    \
    const float* wp_ = wbase + (CIN) * 216;    /* (cin*27)*8 floats */           \
    _Pragma("unroll")                                                            \
    for (int k_ = 0; k_ < 27; ++k_) {                                            \
        const float xq = XV[k_];                                                 \
        const float4 wa = *reinterpret_cast<const float4*>(wp_ + k_ * 8);        \
        const float4 wb = *reinterpret_cast<const float4*>(wp_ + k_ * 8 + 4);    \
        cacc[0] = fmaf(wa.x, xq, cacc[0]);                                       \
        cacc[1] = fmaf(wa.y, xq, cacc[1]);                                       \
        cacc[2] = fmaf(wa.z, xq, cacc[2]);                                       \
        cacc[3] = fmaf(wa.w, xq, cacc[3]);                                       \
        cacc[4] = fmaf(wb.x, xq, cacc[4]);                                       \
        cacc[5] = fmaf(wb.y, xq, cacc[5]);                                       \
        cacc[6] = fmaf(wb.z, xq, cacc[6]);                                       \
        cacc[7] = fmaf(wb.w, xq, cacc[7]);                                       \
    }                                                                            \
    _Pragma("unroll")                                                            \
    for (int ci_ = 0; ci_ < 8; ++ci_) accd[ci_] += (double)cacc[ci_];            \
} while (0)

// ---- fused conv3d + spiking recurrence (no LDS x-staging; x via VMEM) ----
__launch_bounds__(NTHR_, 1)
__global__ void fused_snn(const float* __restrict__ xg,
                          const float* __restrict__ beta_g, const float* __restrict__ bias_g,
                          const float* __restrict__ w_g, const double* __restrict__ d64,
                          const double* __restrict__ inv64, float* __restrict__ out) {
    __shared__ __align__(16) double d_lds[64 * 65];         // 33280 B (padded rows)
    __shared__ unsigned int masks[2][64][2];                // 1024 B

    const int tid = threadIdx.x;
    const int b   = blockIdx.x;          // batch 0..3
    const int ty0 = blockIdx.y * 4;
    const int tx0 = blockIdx.z * 16;

    const int wv   = __builtin_amdgcn_readfirstlane(tid >> 6);  // wave 0..7
    const int lane = tid & 63;
    const int py   = lane >> 4;          // 0..3
    const int px   = lane & 15;          // 0..15
    const int c0   = wv * 8;             // wave owns couts [c0, c0+8)

    // wave's contiguous weight stream (13824 B), wave-uniform -> s_load
    const float* wbase = w_g + (size_t)wv * (K_ * 8);

    for (int i = tid; i < 4096; i += NTHR_)
        d_lds[(i >> 6) * 65 + (i & 63)] = d64[i];
    if (tid < 128) masks[1][tid >> 1][tid & 1] = 0u;  // rbuf for t=0

    // per-lane 3x3 window addressing: clamped offsets + 0/1 masks (no OOB, no branch)
    int a9[9];
    float m9[9];
    const int gy0 = ty0 + py - 1, gx0 = tx0 + px - 1;
#pragma unroll
    for (int dy = 0; dy < 3; ++dy)
#pragma unroll
        for (int dx = 0; dx < 3; ++dx) {
            const int gy = gy0 + dy, gx = gx0 + dx;
            const int cy = gy < 0 ? 0 : (gy > 63 ? 63 : gy);
            const int cx = gx < 0 ? 0 : (gx > 63 ? 63 : gx);
            a9[dy * 3 + dx] = cy * 64 + cx;
            m9[dy * 3 + dx] = (gy >= 0 && gy < 64 && gx >= 0 && gx < 64) ? 1.f : 0.f;
        }

    const double beta = (double)beta_g[0];
    const double omb  = 1.0 - beta;
    double inv_[8], bb[8];
#pragma unroll
    for (int ci = 0; ci < 8; ++ci) {
        inv_[ci] = inv64[c0 + ci];
        bb[ci]   = (double)bias_g[c0 + ci];
    }
    double mem[8];
#pragma unroll
    for (int ci = 0; ci < 8; ++ci) mem[ci] = 0.0;

    __syncthreads();   // d_lds + mask init visible

    for (int t = 0; t < T_; ++t) {
        __syncthreads();   // A: prev mask ORs visible
        if (tid < 128) masks[t & 1][tid >> 1][tid & 1] = 0u;  // clear wbuf

        // slice selectors: clamped z for addressing, zero-masks kill invalid slices
        const int zmc = t > 0 ? t - 1 : 0;
        const int zpc = t < 31 ? t + 1 : 31;
        const float fA = t > 0 ? 1.f : 0.f;
        const float fC = t < 31 ? 1.f : 0.f;
        float mA[9], mC[9];
#pragma unroll
        for (int j = 0; j < 9; ++j) { mA[j] = m9[j] * fA; mC[j] = m9[j] * fC; }

        double accd[8];
#pragma unroll
        for (int ci = 0; ci < 8; ++ci) accd[ci] = 0.0;

        // ---- conv: cin-pipelined VMEM x loads (double-buffered), s_load weights ----
        {
            float xvA[27], xvB[27];
            LOADX(0, xvA);
#pragma unroll 1
            for (int g = 0; g < 8; ++g) {
                LOADX(2 * g + 1, xvB);
                FMACIN(2 * g, xvA);
                if (g < 7) LOADX(2 * g + 2, xvA);
                FMACIN(2 * g + 1, xvB);
            }
        }

        // ---- rst from previous spikes (sparse via bitmask), fp64 d ----
        double rstv[8];
#pragma unroll
        for (int ci = 0; ci < 8; ++ci) rstv[ci] = 0.0;
        const int rb = (t + 1) & 1;
#pragma unroll
        for (int wrd = 0; wrd < 2; ++wrd) {
            unsigned int m = masks[rb][lane][wrd];
            while (m) {
                int bit = __ffs(m) - 1;
                m &= m - 1;
                const double* drow = &d_lds[(wrd * 32 + bit) * 65 + c0];
#pragma unroll
                for (int ci = 0; ci < 8; ++ci) rstv[ci] += drow[ci];
            }
        }

        // ---- membrane update, spike, store ----
        unsigned int nib = 0u;
        const size_t obase = ((size_t)(b * COUT_ + c0) * T_ + t) * (size_t)(H_ * W_)
                           + (size_t)(ty0 + py) * W_ + (tx0 + px);
#pragma unroll
        for (int ci = 0; ci < 8; ++ci) {
            mem[ci] = (mem[ci] - rstv[ci]) * beta + accd[ci] * omb;
            const double mthr = mem[ci] * inv_[ci] - bb[ci];
            const int s = mthr > 0.0 ? 1 : 0;
            out[obase + (size_t)ci * (T_ * H_ * W_)] = (float)s;
            nib |= (unsigned int)s << ci;
        }

        __syncthreads();   // B: clears + mask reads done before ORs
        if (nib) atomicOr(&masks[t & 1][lane][wv >> 2], nib << ((wv & 3) * 8));
    }
}

extern "C" void kernel_launch(void* const* d_in, const int* in_sizes, int n_in,
                              void* d_out, int out_size, void* d_ws, size_t ws_size,
                              hipStream_t stream) {
    const float* x    = (const float*)d_in[0];
    const float* w    = (const float*)d_in[1];
    const float* beta = (const float*)d_in[2];
    const float* bias = (const float*)d_in[3];
    float* out = (float*)d_out;

    float*  w_g   = (float*)d_ws;                                   // 110592 B
    double* d64   = (double*)((char*)d_ws + 110592);                // 32768 B
    double* inv64 = (double*)((char*)d_ws + 110592 + 32768);        // 512 B

    prep<<<dim3(64), dim3(64), 0, stream>>>(w, w_g, d64, inv64);
    fused_snn<<<dim3(4, 16, 4), dim3(NTHR_), 0, stream>>>(x, beta, bias, w_g, d64, inv64, out);
}

// Round 18
// 522.847 us; speedup vs baseline: 2.7281x; 2.7281x over previous
//
#include <hip/hip_runtime.h>
#include <cstdint>
#include <cstddef>

#define H_ 64
#define W_ 64
#define T_ 32
#define CIN_ 16
#define COUT_ 64
#define K_ 432
#define TH_ 4
#define TW_ 16
#define WR_ 6          // window rows: 4 + 2 halo
#define WC_ 24         // padded window cols (18 used)
#define WSZ_ (WR_ * WC_)     // 144
#define XTOT_ (CIN_ * WSZ_)  // 2304
#define NSLOT_ 4
#define NTHR_ 1024

// ---- prep: w_g[cout_grp][k][4] f32 (wave-contiguous), Gram d64, inv64 ----
__global__ void prep(const float* __restrict__ w, float* __restrict__ w_g,
                     double* __restrict__ d64, double* __restrict__ inv64) {
    const int i = blockIdx.x;   // cout row
    const int j = threadIdx.x;  // 0..63
    const float* wi = w + i * K_;
    const float* wj = w + j * K_;
    double acc = 0.0;
    for (int k = 0; k < K_; ++k) acc += (double)wi[k] * (double)wj[k];
    d64[i * 64 + j] = acc;
    if (i == j) inv64[i] = 1.0 / (acc + 1e-8);
    // grouped layout: w_g[(g*K_ + k)*4 + (cout&3)], g = cout>>2
    for (int k = j; k < K_; k += 64)
        w_g[(((i >> 2) * K_) + k) * 4 + (i & 3)] = wi[k];
}

// ---- fused conv3d + spiking recurrence (R8 + single-barrier 3-phase masks) ----
__launch_bounds__(NTHR_, 1)
__global__ void fused_snn(const float* __restrict__ xg,
                          const float* __restrict__ beta_g, const float* __restrict__ bias_g,
                          const float* __restrict__ w_g, const double* __restrict__ d64,
                          const double* __restrict__ inv64, float* __restrict__ out) {
    __shared__ __align__(16) float x_win[NSLOT_ * XTOT_];   // 36864 B
    __shared__ __align__(16) double d_lds[64 * 65];         // 33280 B (padded rows)
    __shared__ unsigned int masks[3][64][2];                // 1536 B, 3-phase

    const int tid = threadIdx.x;
    const int b   = blockIdx.x;          // batch 0..3
    const int ty0 = blockIdx.y * TH_;
    const int tx0 = blockIdx.z * TW_;

    const int wv   = __builtin_amdgcn_readfirstlane(tid >> 6);  // wave 0..15
    const int lane = tid & 63;
    const int py   = lane >> 4;          // 0..3
    const int px   = lane & 15;          // 0..15
    const int c0   = wv * 4;             // wave owns couts [c0, c0+4)
    const int xoff = py * WC_ + px;

    // wave's contiguous weight stream (6912 B), wave-uniform -> s_load
    const float* wbase = w_g + (size_t)wv * (K_ * 4);

    for (int i = tid; i < 4096; i += NTHR_)
        d_lds[(i >> 6) * 65 + (i & 63)] = d64[i];
    if (tid < 384) masks[tid / 128][(tid % 128) >> 1][tid & 1] = 0u;  // clear all 3 bufs

    // stage slices z=0,1 into slots 0,1
    for (int z = 0; z < 2; ++z) {
        for (int i = tid; i < XTOT_; i += NTHR_) {
            int cin = i / WSZ_;
            int r2  = i - cin * WSZ_;
            int yy  = r2 / WC_;
            int xx  = r2 - yy * WC_;
            if (xx >= TW_ + 2) continue;        // pad cols never read
            int gy = ty0 - 1 + yy, gx = tx0 - 1 + xx;
            float v = 0.f;
            if (gy >= 0 && gy < H_ && gx >= 0 && gx < W_)
                v = xg[((size_t)(b * CIN_ + cin) * T_ + z) * (H_ * W_) + gy * W_ + gx];
            x_win[z * XTOT_ + i] = v;
        }
    }

    const double beta = (double)beta_g[0];
    const double omb  = 1.0 - beta;
    double inv_[4], bb[4];
#pragma unroll
    for (int ci = 0; ci < 4; ++ci) {
        inv_[ci] = inv64[c0 + ci];
        bb[ci]   = (double)bias_g[c0 + ci];
    }
    double mem[4];
#pragma unroll
    for (int ci = 0; ci < 4; ++ci) mem[ci] = 0.0;

    // prefetch/staging index precompute (3 elems max per thread)
    int  pf_loff[3];
    size_t pf_goff[3];
    bool pf_use[3], pf_in[3];
#pragma unroll
    for (int r = 0; r < 3; ++r) {
        int i = tid + r * NTHR_;
        int cin = i / WSZ_;
        int r2  = i - cin * WSZ_;
        int yy  = r2 / WC_;
        int xx  = r2 - yy * WC_;
        pf_loff[r] = i;
        int gy = ty0 - 1 + yy, gx = tx0 - 1 + xx;
        bool ok = (i < XTOT_) && (xx < TW_ + 2);
        pf_use[r] = ok;
        pf_in[r]  = ok && gy >= 0 && gy < H_ && gx >= 0 && gx < W_;
        pf_goff[r] = (size_t)(b * CIN_ + cin) * (T_ * H_ * W_) + (size_t)gy * W_ + gx;
    }

    for (int t = 0; t < T_; ++t) {
        __syncthreads();   // THE barrier: prev XSTORE + prev ORs + prev reads all done
        // clear next iteration's write-buffer (nobody touches it this iter)
        if (tid < 128) masks[(t + 1) % 3][tid >> 1][tid & 1] = 0u;

        // prefetch slice z=t+2 into regs (hidden under conv)
        float R[3];
        const int zp = t + 2;
        if (zp < T_) {
#pragma unroll
            for (int r = 0; r < 3; ++r) {
                R[r] = 0.f;
                if (pf_in[r]) R[r] = xg[pf_goff[r] + (size_t)zp * (H_ * W_)];
            }
        }

        // ---- conv: fp32 products, per-cin fp64 accumulate (R8 schedule) ----
        double accd[4];
#pragma unroll
        for (int ci = 0; ci < 4; ++ci) accd[ci] = 0.0;

        int slot_[3]; bool zok[3];
#pragma unroll
        for (int dz = 0; dz < 3; ++dz) {
            int z = t - 1 + dz;
            zok[dz]  = (z >= 0 && z < T_);
            slot_[dz] = zok[dz] ? (z & 3) : 0;
        }

        for (int cin = 0; cin < CIN_; ++cin) {
            // batch ALL x reads for this cin first (one DS-latency exposure)
            float xv[3][9];
#pragma unroll
            for (int dz = 0; dz < 3; ++dz) {
                if (!zok[dz]) continue;
                const float* xs = &x_win[slot_[dz] * XTOT_ + cin * WSZ_] + xoff;
#pragma unroll
                for (int dy = 0; dy < 3; ++dy) {
                    xv[dz][dy * 3 + 0] = xs[dy * WC_ + 0];
                    xv[dz][dy * 3 + 1] = xs[dy * WC_ + 1];
                    xv[dz][dy * 3 + 2] = xs[dy * WC_ + 2];
                }
            }
            float cacc[4];
#pragma unroll
            for (int ci = 0; ci < 4; ++ci) cacc[ci] = 0.f;
#pragma unroll
            for (int dz = 0; dz < 3; ++dz) {
                if (!zok[dz]) continue;
                // contiguous 144B weight plane for this (cin,dz)
                const float* wp = wbase + (cin * 27 + dz * 9) * 4;
#pragma unroll
                for (int dy = 0; dy < 3; ++dy) {
                    const float4 w0 = *reinterpret_cast<const float4*>(wp + (dy * 3 + 0) * 4);
                    const float4 w1 = *reinterpret_cast<const float4*>(wp + (dy * 3 + 1) * 4);
                    const float4 w2 = *reinterpret_cast<const float4*>(wp + (dy * 3 + 2) * 4);
                    const float xv0 = xv[dz][dy * 3 + 0];
                    const float xv1 = xv[dz][dy * 3 + 1];
                    const float xv2 = xv[dz][dy * 3 + 2];
                    cacc[0] = fmaf(w0.x, xv0, cacc[0]);
                    cacc[1] = fmaf(w0.y, xv0, cacc[1]);
                    cacc[2] = fmaf(w0.z, xv0, cacc[2]);
                    cacc[3] = fmaf(w0.w, xv0, cacc[3]);
                    cacc[0] = fmaf(w1.x, xv1, cacc[0]);
                    cacc[1] = fmaf(w1.y, xv1, cacc[1]);
                    cacc[2] = fmaf(w1.z, xv1, cacc[2]);
                    cacc[3] = fmaf(w1.w, xv1, cacc[3]);
                    cacc[0] = fmaf(w2.x, xv2, cacc[0]);
                    cacc[1] = fmaf(w2.y, xv2, cacc[1]);
                    cacc[2] = fmaf(w2.z, xv2, cacc[2]);
                    cacc[3] = fmaf(w2.w, xv2, cacc[3]);
                }
            }
#pragma unroll
            for (int ci = 0; ci < 4; ++ci) accd[ci] += (double)cacc[ci];
        }

        // ---- rst from prev iteration's spikes: buf[(t-1)%3] == buf[(t+2)%3] ----
        double rstv[4];
#pragma unroll
        for (int ci = 0; ci < 4; ++ci) rstv[ci] = 0.0;
        const int rb = (t + 2) % 3;
#pragma unroll
        for (int wrd = 0; wrd < 2; ++wrd) {
            unsigned int m = masks[rb][lane][wrd];
            while (m) {
                int bit = __ffs(m) - 1;
                m &= m - 1;
                const double* drow = &d_lds[(wrd * 32 + bit) * 65 + c0];
#pragma unroll
                for (int ci = 0; ci < 4; ++ci) rstv[ci] += drow[ci];
            }
        }

        // ---- membrane update, spike, store ----
        unsigned int nib = 0u;
        const size_t obase = ((size_t)(b * COUT_ + c0) * T_ + t) * (size_t)(H_ * W_)
                           + (size_t)(ty0 + py) * W_ + (tx0 + px);
#pragma unroll
        for (int ci = 0; ci < 4; ++ci) {
            mem[ci] = (mem[ci] - rstv[ci]) * beta + accd[ci] * omb;
            const double mthr = mem[ci] * inv_[ci] - bb[ci];
            const int s = mthr > 0.0 ? 1 : 0;
            out[obase + (size_t)ci * (T_ * H_ * W_)] = (float)s;
            nib |= (unsigned int)s << ci;
        }

        // OR into this iteration's buffer (cleared last iter; read next iter)
        if (nib) atomicOr(&masks[t % 3][lane][wv >> 3], nib << ((wv & 7) * 4));

        // write prefetched slice z=t+2 into slot (t+2)&3 (never read this iter)
        if (zp < T_) {
            const int so = (zp & 3) * XTOT_;
#pragma unroll
            for (int r = 0; r < 3; ++r)
                if (pf_use[r]) x_win[so + pf_loff[r]] = R[r];
        }
    }
}

extern "C" void kernel_launch(void* const* d_in, const int* in_sizes, int n_in,
                              void* d_out, int out_size, void* d_ws, size_t ws_size,
                              hipStream_t stream) {
    const float* x    = (const float*)d_in[0];
    const float* w    = (const float*)d_in[1];
    const float* beta = (const float*)d_in[2];
    const float* bias = (const float*)d_in[3];
    float* out = (float*)d_out;

    float*  w_g   = (float*)d_ws;                                   // 110592 B
    double* d64   = (double*)((char*)d_ws + 110592);                // 32768 B
    double* inv64 = (double*)((char*)d_ws + 110592 + 32768);        // 512 B

    prep<<<dim3(64), dim3(64), 0, stream>>>(w, w_g, d64, inv64);
    fused_snn<<<dim3(4, 16, 4), dim3(NTHR_), 0, stream>>>(x, beta, bias, w_g, d64, inv64, out);
}